// Round 5
// baseline (1118.680 us; speedup 1.0000x reference)
//
#include <hip/hip_runtime.h>
#include <math.h>

typedef unsigned short u16;
typedef __attribute__((ext_vector_type(4))) float f32x4;
typedef __attribute__((ext_vector_type(8))) __bf16 bf16x8;
typedef __attribute__((ext_vector_type(8))) u16 u16x8;
typedef __attribute__((ext_vector_type(4))) u16 u16x4;

__device__ __forceinline__ float bf2f(u16 v) {
    unsigned int u = ((unsigned int)v) << 16;
    return __builtin_bit_cast(float, u);
}
__device__ __forceinline__ u16 f2bf(float f) {
    unsigned int x = __builtin_bit_cast(unsigned int, f);
    x += 0x7fffu + ((x >> 16) & 1u);   // RNE
    return (u16)(x >> 16);
}

__device__ __forceinline__ void load_lds16(const u16* g, u16* l) {
    __builtin_amdgcn_global_load_lds((const __attribute__((address_space(1))) void*)g,
                                     (__attribute__((address_space(3))) void*)l, 16, 0, 0);
}

#define WAIT_VM(N) asm volatile("s_waitcnt vmcnt(" #N ")" ::: "memory")
#define LGKM0_SB() do { asm volatile("s_waitcnt lgkmcnt(0)" ::: "memory"); \
                        __builtin_amdgcn_sched_barrier(0); } while (0)
#define MFMA16(d, x, y) d = __builtin_amdgcn_mfma_f32_16x16x32_bf16(x, y, d, 0, 0, 0)

// ---------------------------------------------------------------------------
// f32 -> bf16 weight conversion
// ---------------------------------------------------------------------------
__global__ __launch_bounds__(256) void cvt_kernel(const float* __restrict__ in,
                                                  u16* __restrict__ out, int n)
{
    const int i = (blockIdx.x * 256 + threadIdx.x) * 4;
    if (i >= n) return;
    const float4 f = *(const float4*)(in + i);
    u16x4 o;
    o[0] = f2bf(f.x); o[1] = f2bf(f.y); o[2] = f2bf(f.z); o[3] = f2bf(f.w);
    *(u16x4*)(out + i) = o;
}

// ---------------------------------------------------------------------------
// 256x(NFR*64) GEMM, BK=32, DEEP-PIPELINED (quad/triple-buffered LDS).
// C[M][N] = epi( A[M][K](bf16, lda) * W[N][K](bf16, ldw)^T + bias )
//
// 8 waves (2M x 4N), per-wave 128x(NFR*16) output, acc[8][NFR]. BK=32.
// Stages: NFR=4 -> 4 stages x 32 KB = 128 KB (prefetch distance 3 tiles);
//         NFR=2 -> 3 stages x 24 KB =  72 KB (distance 2; 2 blocks/CU).
// Per tile: NFR=4: 2 phases x 16 MFMA; NFR=2: 1 phase x 16 MFMA. Each phase:
//   ds_reads ; issue global_load_lds prefetch (tile t+PD) ; s_barrier ;
//   lgkmcnt(0)+sched_barrier ; setprio(1) ; 16 MFMA ; setprio(0) ;
//   [counted vmcnt at tile end: NFR4 vmcnt(8), NFR2 vmcnt(3)] ; s_barrier
// Counted vmcnt drains exactly tile t+1's loads (the following s_barrier
// turns each wave's private vmcnt guarantee into a cross-wave one); deeper
// prefetches stay in flight across barriers (never vmcnt(0) mid-loop).
//
// LDS stage: A [256 rows][32 u16] + B [(NFR*64) rows][32 u16], 64-B rows.
// Swizzle: row r's stored 16-B seg s holds global seg (s - ((r>>1)&3))&3,
// realized by rotating the GLOBAL source col per lane (linear LDS dest);
// ds_read uses slot s=(quad+(colq>>1))&3 -> conflict-bounded (2-way) and
// returns global k-seg = quad.
//
// EPI 0: qkv scatter (Q/K direct; Vt via LDS transpose). EPI 1: + residual
// (RES=1 f32, RES=2 bf16). EPI 2: exact GELU. OF32: O0 is float*.
// ---------------------------------------------------------------------------
template<int EPI, int RES, bool OF32, int NFR>
__global__ __launch_bounds__(512, 2) void gemm32(
    const u16* __restrict__ A, const u16* __restrict__ W,
    const float* __restrict__ bias,
    const float* __restrict__ resf, const u16* __restrict__ resb,
    void* __restrict__ O0v, u16* __restrict__ O1, u16* __restrict__ O2,
    int M, int N, int K, int lda, int ldw, int mbase)
{
    constexpr int STG  = 8192 + NFR * 2048;      // u16 per stage
    constexpr int NSTG = (NFR == 4) ? 4 : 3;
    constexpr int PD   = NSTG - 1;               // prefetch distance (tiles)
    __shared__ u16 S[NSTG * STG];
    const int tid  = threadIdx.x;
    const int w    = tid >> 6;
    const int l    = tid & 63;
    const int colq = l & 15;
    const int quad = l >> 4;
    const int w3   = w & 3;
    const int wm   = (w >> 2) * 128;      // wave M offset
    const int wn   = w3 * (NFR * 16);     // wave N offset

    // T1: XCD-aware bijective block swizzle (all launches have nwg % 8 == 0)
    const int nX  = (int)gridDim.x;
    const int nwg = nX * (int)gridDim.y;
    const int did = (int)blockIdx.y * nX + (int)blockIdx.x;
    const int q8  = nwg >> 3;
    const int wg  = (nwg & 7) ? did : ((did & 7) * q8 + (did >> 3));
    const int bm  = wg / nX;
    const int bn  = wg - bm * nX;
    const int m0  = bm * 256, n0 = bn * (NFR * 64);

    // -------- staging descriptors (per thread: A x2 + B x{2|1} per tile) ---
    const int ra  = w * 16 + (l >> 2);                       // row in 128-half
    const int sa  = (((l & 3) - ((l >> 3) & 3)) & 3) * 8;    // rotated src col
    const u16* gA[2];
    gA[0] = A + (size_t)(m0 + ra) * lda + sa;
    gA[1] = A + (size_t)(m0 + 128 + ra) * lda + sa;
    const u16* gB[2];
    gB[0] = W + (size_t)(n0 + ra) * ldw + sa;
    gB[1] = (NFR == 4) ? (W + (size_t)(n0 + 128 + ra) * ldw + sa) : nullptr;
    const int dw = w * 512;                                  // dest base (u16)

    // -------- fragment read col slot (rotation swizzle, u16 units) ---------
    const int cs = ((quad + (colq >> 1)) & 3) * 8;

    f32x4 acc[8][NFR] = {};

    // -------- prologue: stage tiles 0..PD-1 --------------------------------
#pragma unroll
    for (int s = 0; s < PD; ++s) {
        const int kk = s << 5;
        u16* Sp = S + s * STG;
        load_lds16(gA[0] + kk, Sp + dw);
        load_lds16(gA[1] + kk, Sp + 4096 + dw);
        load_lds16(gB[0] + kk, Sp + 8192 + dw);
        if constexpr (NFR == 4) load_lds16(gB[1] + kk, Sp + 8192 + 4096 + dw);
    }
    if constexpr (NFR == 4) { WAIT_VM(8); } else { WAIT_VM(3); }   // tile 0 resident
    __builtin_amdgcn_s_barrier();

    const int NT = K >> 5;
    for (int t = 0; t < NT; ++t) {
        u16* Sc = S + (t % NSTG) * STG;
        u16* Sp = S + ((t + PD) % NSTG) * STG;
        const int  kk = (t + PD) << 5;
        const bool pf = (t + PD) < NT;

        bf16x8 a[8], p0b0, p0b1;
        // ---- P0: all m x n-frags {0,1} ----
#pragma unroll
        for (int m = 0; m < 8; ++m)
            a[m] = *(const bf16x8*)(Sc + (wm + m * 16 + colq) * 32 + cs);
        p0b0 = *(const bf16x8*)(Sc + 8192 + (wn + colq) * 32 + cs);
        p0b1 = *(const bf16x8*)(Sc + 8192 + (wn + 16 + colq) * 32 + cs);
        if (pf) {
            load_lds16(gA[0] + kk, Sp + dw);
            load_lds16(gA[1] + kk, Sp + 4096 + dw);
            if constexpr (NFR == 2) load_lds16(gB[0] + kk, Sp + 8192 + dw);
        }
        __builtin_amdgcn_s_barrier();
        LGKM0_SB();
        __builtin_amdgcn_s_setprio(1);
#pragma unroll
        for (int m = 0; m < 8; ++m) {
            MFMA16(acc[m][0], a[m], p0b0);
            MFMA16(acc[m][1], a[m], p0b1);
        }
        __builtin_amdgcn_s_setprio(0);
        if constexpr (NFR == 4) {
            __builtin_amdgcn_s_barrier();

            // ---- P1: all m x n-frags {2,3} ----
            bf16x8 p1b0, p1b1;
            p1b0 = *(const bf16x8*)(Sc + 8192 + (wn + 32 + colq) * 32 + cs);
            p1b1 = *(const bf16x8*)(Sc + 8192 + (wn + 48 + colq) * 32 + cs);
            if (pf) {
                load_lds16(gB[0] + kk, Sp + 8192 + dw);
                load_lds16(gB[1] + kk, Sp + 8192 + 4096 + dw);
            }
            __builtin_amdgcn_s_barrier();
            LGKM0_SB();
            __builtin_amdgcn_s_setprio(1);
#pragma unroll
            for (int m = 0; m < 8; ++m) {
                MFMA16(acc[m][2], a[m], p1b0);
                MFMA16(acc[m][3], a[m], p1b1);
            }
            __builtin_amdgcn_s_setprio(0);
            if ((t + 3) < NT)      { WAIT_VM(8); }   // drain t+1; t+2,t+3 in flight
            else if ((t + 2) < NT) { WAIT_VM(4); }
            else if ((t + 1) < NT) { WAIT_VM(0); }
        } else {
            if ((t + 2) < NT)      { WAIT_VM(3); }   // drain t+1; t+2 in flight
            else if ((t + 1) < NT) { WAIT_VM(0); }
        }
        __builtin_amdgcn_s_barrier();
    }

    // -------- epilogue ------------------------------------------------------
    // C/D layout (m89): row = quad*4+i, col = colq within each 16x16 frag.
    if constexpr (EPI == 0) {
        if (n0 >= 2048) {
            // Vt block: LDS transpose -> coalesced stores along t.
            __syncthreads();
#pragma unroll
            for (int nf = 0; nf < NFR; ++nf) {
                const int cl = wn + nf * 16 + colq;
                const float bz = bias[n0 + cl];
                const int swz = (cl & 7) << 3;
#pragma unroll
                for (int mf = 0; mf < 8; ++mf) {
                    const int rb = wm + mf * 16 + quad * 4;
                    u16x4 pk;
#pragma unroll
                    for (int i = 0; i < 4; ++i) pk[i] = f2bf(acc[mf][nf][i] + bz);
                    *(u16x4*)(S + cl * 256 + (rb ^ swz)) = pk;
                }
            }
            __syncthreads();
            const int cl   = tid >> 1;
            const int c    = n0 + cl;
            const int head = (c >> 6) & 15;
            const int d    = c & 63;
            const int rg0  = mbase + m0;
            const int bh   = (rg0 >> 12) * 16 + head;
            const int half = tid & 1;
            const int swz  = (cl & 7) << 3;
            u16* op = O2 + ((size_t)bh * 64 + d) * 4096 + (rg0 & 4095) + half * 128;
#pragma unroll
            for (int j = 0; j < 16; ++j) {
                const int r0 = half * 128 + j * 8;
                *(u16x8*)(op + j * 8) = *(const u16x8*)(S + cl * 256 + (r0 ^ swz));
            }
            return;
        }
    }
#pragma unroll
    for (int nf = 0; nf < NFR; ++nf) {
        const int c = n0 + wn + nf * 16 + colq;
        const float bz = bias ? bias[c] : 0.f;
#pragma unroll
        for (int mf = 0; mf < 8; ++mf) {
#pragma unroll
            for (int i = 0; i < 4; ++i) {
                const int r = m0 + wm + mf * 16 + quad * 4 + i;
                float v = acc[mf][nf][i] + bz;
                if constexpr (EPI == 0) {
                    const int head = (c >> 6) & 15;
                    const int d    = c & 63;
                    const int rg   = mbase + r;
                    const int tt   = rg & 4095;
                    const int bh   = (rg >> 12) * 16 + head;
                    const u16 val = f2bf(v);
                    if (c < 1024) ((u16*)O0v)[((size_t)bh * 4096 + tt) * 64 + d] = val; // Q
                    else          O1[((size_t)bh * 4096 + tt) * 64 + d] = val;          // K
                } else {
                    const size_t idx = (size_t)r * N + c;
                    if constexpr (RES == 1) v += resf[idx];
                    if constexpr (RES == 2) v += bf2f(resb[idx]);
                    if constexpr (EPI == 2) v = 0.5f * v * (1.0f + erff(v * 0.70710678118654752f));
                    if constexpr (OF32) ((float*)O0v)[idx] = v;
                    else                ((u16*)O0v)[idx] = f2bf(v);
                }
            }
        }
    }
}

// ---------------------------------------------------------------------------
// LayerNorm: one wave per row of 1024. F32IN: x is f32 (LN1); else bf16 (LN2).
// ---------------------------------------------------------------------------
template<bool F32IN>
__global__ __launch_bounds__(256) void ln_kernel(
    const void* __restrict__ xin, const float* __restrict__ w,
    const float* __restrict__ b, u16* __restrict__ out)
{
    const int wave = threadIdx.x >> 6, lane = threadIdx.x & 63;
    const size_t row = (size_t)blockIdx.x * 4 + wave;
    float v[16];
    if constexpr (F32IN) {
        const float* xr = (const float*)xin + row * 1024 + lane * 16;
#pragma unroll
        for (int j = 0; j < 4; ++j) {
            const float4 f = *(const float4*)(xr + j * 4);
            v[j * 4 + 0] = f.x; v[j * 4 + 1] = f.y; v[j * 4 + 2] = f.z; v[j * 4 + 3] = f.w;
        }
    } else {
        const u16* xr = (const u16*)xin + row * 1024 + lane * 16;
        u16x8 xa = *(const u16x8*)xr;
        u16x8 xb = *(const u16x8*)(xr + 8);
#pragma unroll
        for (int i = 0; i < 8; ++i) { v[i] = bf2f(xa[i]); v[8 + i] = bf2f(xb[i]); }
    }
    float s = 0.f, s2 = 0.f;
#pragma unroll
    for (int i = 0; i < 16; ++i) { s += v[i]; s2 += v[i] * v[i]; }
#pragma unroll
    for (int m = 32; m >= 1; m >>= 1) { s += __shfl_xor(s, m, 64); s2 += __shfl_xor(s2, m, 64); }
    const float mu  = s * (1.0f / 1024.0f);
    const float var = s2 * (1.0f / 1024.0f) - mu * mu;
    const float rs  = rsqrtf(var + 1e-5f);
    const float* wp = w + lane * 16;
    const float* bp = b + lane * 16;
    u16x8 oa, ob;
#pragma unroll
    for (int i = 0; i < 8; ++i) {
        oa[i] = f2bf((v[i]     - mu) * rs * wp[i]     + bp[i]);
        ob[i] = f2bf((v[8 + i] - mu) * rs * wp[8 + i] + bp[8 + i]);
    }
    u16* orow = out + row * 1024 + lane * 16;
    *(u16x8*)orow       = oa;
    *(u16x8*)(orow + 8) = ob;
}

// ---------------------------------------------------------------------------
// Local attention, flash-style over 2 key-chunks of 192.
// Round-2 body (conditional loads; no spills) + occupancy 6 blocks/CU
// (150 KB LDS) + exp2f with folded softmax scale.
// ---------------------------------------------------------------------------
__global__ __launch_bounds__(256, 6) void attn_kernel(
    const u16* __restrict__ Q, const u16* __restrict__ Kb,
    const u16* __restrict__ Vt, u16* __restrict__ out)
{
    __shared__ u16 Ps[4][16 * 200];
    const int tid  = threadIdx.x;
    const int wave = tid >> 6;
    const int lane = tid & 63;
    const int colq = lane & 15;
    const int quad = lane >> 4;
    const float C2 = 0.18033688011112042f;   // 0.125 * log2(e)

    const int f   = blockIdx.x;            // 0..4095
    const int xcd = f & 7;
    const int s8  = f >> 3;                // 0..511
    const int bh  = s8 >> 3;               // 0..63
    const int tb  = (s8 & 7) + 8 * xcd;    // 0..63
    const int qrow0 = tb * 64 + wave * 16;
    const int nb    = tb >> 1;
    const int key0  = nb * 128 - 128;
    const int nt_lo = (nb == 0) ? 8 : 0;
    const int nt_hi = (nb == 31) ? 16 : 24;

    const u16* qp = Q + ((size_t)bh * 4096 + qrow0 + colq) * 64 + quad * 8;
    bf16x8 aq0 = *(const bf16x8*)qp;
    bf16x8 aq1 = *(const bf16x8*)(qp + 32);

    float m_i[4], l_i[4];
    f32x4 o[4] = {};
#pragma unroll
    for (int i = 0; i < 4; ++i) { m_i[i] = -3.0e38f; l_i[i] = 0.f; }

    u16* Psw = &Ps[wave][0];

#pragma unroll
    for (int c = 0; c < 2; ++c) {
        const int lo = (c == 0) ? nt_lo : 12;
        const int hi = (c == 0) ? ((nt_hi < 12) ? nt_hi : 12) : nt_hi;

        f32x4 sc[12];
#pragma unroll
        for (int j = 0; j < 12; ++j) sc[j] = (f32x4){0.f, 0.f, 0.f, 0.f};
#pragma unroll
        for (int j = 0; j < 12; ++j) {
            const int nt = c * 12 + j;
            if (nt >= lo && nt < hi) {
                const u16* kp = Kb + ((size_t)bh * 4096 + key0 + nt * 16 + colq) * 64 + quad * 8;
                bf16x8 b0 = *(const bf16x8*)kp;
                bf16x8 b1 = *(const bf16x8*)(kp + 32);
                f32x4 z = {0.f, 0.f, 0.f, 0.f};
                z = __builtin_amdgcn_mfma_f32_16x16x32_bf16(aq0, b0, z, 0, 0, 0);
                z = __builtin_amdgcn_mfma_f32_16x16x32_bf16(aq1, b1, z, 0, 0, 0);
                sc[j] = z;
            }
        }
        float mc[4];
#pragma unroll
        for (int i = 0; i < 4; ++i) mc[i] = -3.0e38f;
#pragma unroll
        for (int j = 0; j < 12; ++j) {
            const int nt = c * 12 + j;
            if (nt >= lo && nt < hi)
#pragma unroll
                for (int i = 0; i < 4; ++i) mc[i] = fmaxf(mc[i], sc[j][i]);
        }
#pragma unroll
        for (int i = 0; i < 4; ++i)
#pragma unroll
            for (int m = 8; m >= 1; m >>= 1) mc[i] = fmaxf(mc[i], __shfl_xor(mc[i], m, 64));
        float a_i[4], psum[4];
#pragma unroll
        for (int i = 0; i < 4; ++i) {
            const float mn = fmaxf(m_i[i], mc[i]);
            a_i[i] = exp2f((m_i[i] - mn) * C2);
            m_i[i] = mn;
            psum[i] = 0.f;
        }
#pragma unroll
        for (int j = 0; j < 12; ++j) {
            const int nt = c * 12 + j;
            if (nt >= lo && nt < hi) {
#pragma unroll
                for (int i = 0; i < 4; ++i) {
                    const float p = exp2f((sc[j][i] - m_i[i]) * C2);
                    psum[i] += p;
                    Psw[(quad * 4 + i) * 200 + j * 16 + colq] = f2bf(p);
                }
            }
        }
#pragma unroll
        for (int i = 0; i < 4; ++i)
#pragma unroll
            for (int m = 8; m >= 1; m >>= 1) psum[i] += __shfl_xor(psum[i], m, 64);
#pragma unroll
        for (int i = 0; i < 4; ++i) l_i[i] = l_i[i] * a_i[i] + psum[i];
#pragma unroll
        for (int dt = 0; dt < 4; ++dt)
#pragma unroll
            for (int i = 0; i < 4; ++i) o[dt][i] *= a_i[i];
        const int klo = (lo - c * 12) >> 1;
        const int khi = (hi - c * 12) >> 1;
#pragma unroll
        for (int k6 = 0; k6 < 6; ++k6) {
            if (k6 >= klo && k6 < khi) {
                bf16x8 ap = *(const bf16x8*)(Psw + colq * 200 + k6 * 32 + quad * 8);
                const int kkk = key0 + (c * 6 + k6) * 32 + quad * 8;
#pragma unroll
                for (int dt = 0; dt < 4; ++dt) {
                    const u16* vp = Vt + ((size_t)bh * 64 + dt * 16 + colq) * 4096 + kkk;
                    bf16x8 bv = *(const bf16x8*)vp;
                    o[dt] = __builtin_amdgcn_mfma_f32_16x16x32_bf16(ap, bv, o[dt], 0, 0, 0);
                }
            }
        }
    }

    const int bb = bh >> 4, hh = bh & 15;
#pragma unroll
    for (int i = 0; i < 4; ++i) {
        const float inv = 1.0f / fmaxf(l_i[i], 1e-20f);
        const int t = qrow0 + quad * 4 + i;
        u16* op = out + ((size_t)(bb * 4096 + t)) * 1024 + hh * 64;
#pragma unroll
        for (int dt = 0; dt < 4; ++dt) op[dt * 16 + colq] = f2bf(o[dt][i] * inv);
    }
}

// ---------------------------------------------------------------------------
extern "C" void kernel_launch(void* const* d_in, const int* in_sizes, int n_in,
                              void* d_out, int out_size, void* d_ws, size_t ws_size,
                              hipStream_t stream)
{
    const float* x      = (const float*)d_in[0];
    const float* ln1_w  = (const float*)d_in[1];
    const float* ln1_b  = (const float*)d_in[2];
    const float* qkv_w  = (const float*)d_in[3];
    const float* qkv_b  = (const float*)d_in[4];
    const float* proj_w = (const float*)d_in[5];
    const float* proj_b = (const float*)d_in[6];
    const float* ln2_w  = (const float*)d_in[7];
    const float* ln2_b  = (const float*)d_in[8];
    const float* fc1_w  = (const float*)d_in[9];
    const float* fc1_b  = (const float*)d_in[10];
    const float* fc2_w  = (const float*)d_in[11];
    const float* fc2_b  = (const float*)d_in[12];
    float* outp = (float*)d_out;

    if (ws_size < 134217728u) return;
    char* ws = (char*)d_ws;
    u16* R0 = (u16*)(ws);               // bf16 weights (25.2 MB)
    u16* R1 = (u16*)(ws + 33554432);    // Q  -> x2 (bf16)
    u16* R2 = (u16*)(ws + 67108864);    // K  -> h lower half
    u16* R3 = (u16*)(ws + 100663296);   // Vt -> h upper half
    // d_out scratch: xn @ [0:33.5M), attn/yn @ [33.5M:67M).
    u16* xnc    = (u16*)d_out;
    u16* attn_o = (u16*)((char*)d_out + 33554432);

    u16* qkvwb  = R0;
    u16* projwb = R0 + 3145728;
    u16* fc1wb  = R0 + 4194304;
    u16* fc2wb  = R0 + 8388608;
    u16* Qb = R1, *Kb = R2, *Vtb = R3;
    u16* x2 = R1;                       // Q dead after attn
    u16* yn = attn_o;                   // attn_o dead after proj
    u16* hb = R2;                       // K,Vt dead after attn: 67 MB contiguous

    // 1. weights f32 -> bf16
    cvt_kernel<<<3072, 256, 0, stream>>>(qkv_w, qkvwb, 3145728);
    cvt_kernel<<<1024, 256, 0, stream>>>(proj_w, projwb, 1048576);
    cvt_kernel<<<4096, 256, 0, stream>>>(fc1_w, fc1wb, 4194304);
    cvt_kernel<<<4096, 256, 0, stream>>>(fc2_w, fc2wb, 4194304);
    // 2. LN1: x -> xn
    ln_kernel<true><<<4096, 256, 0, stream>>>(x, ln1_w, ln1_b, xnc);
    // 3. qkv GEMM + scatter (768 blocks)
    gemm32<0, 0, false, 4><<<dim3(12, 64), 512, 0, stream>>>(
        xnc, qkvwb, qkv_b, nullptr, nullptr, Qb, Kb, Vtb,
        16384, 3072, 1024, 1024, 1024, 0);
    // 4. local attention -> attn_o
    attn_kernel<<<4096, 256, 0, stream>>>(Qb, Kb, Vtb, attn_o);
    // 5. proj + residual(x, f32) -> x2 bf16 (256 blocks)
    gemm32<1, 1, false, 4><<<dim3(4, 64), 512, 0, stream>>>(
        attn_o, projwb, proj_b, x, nullptr, x2, nullptr, nullptr,
        16384, 1024, 1024, 1024, 1024, 0);
    // 6. LN2: x2 -> yn
    ln_kernel<false><<<4096, 256, 0, stream>>>(x2, ln2_w, ln2_b, yn);
    // 7. FFN in 2 M-chunks of 8192 rows; h (67 MB) in R2+R3.
    //    fc1: 512 blocks (BN=256). fc2: BN=128 variant -> 8x32 = 256 blocks
    //    (full K=4096 single pass).
    for (int ci = 0; ci < 2; ++ci) {
        const size_t off = (size_t)ci * 8192 * 1024;
        gemm32<2, 0, false, 4><<<dim3(16, 32), 512, 0, stream>>>(
            yn + off, fc1wb, fc1_b, nullptr, nullptr, hb, nullptr, nullptr,
            8192, 4096, 1024, 1024, 1024, 0);
        gemm32<1, 2, true, 2><<<dim3(8, 32), 512, 0, stream>>>(
            hb, fc2wb, fc2_b, nullptr, x2 + off, outp + off, nullptr, nullptr,
            8192, 1024, 4096, 4096, 4096, 0);
    }
}

// Round 6
// 953.074 us; speedup vs baseline: 1.1738x; 1.1738x over previous
//
#include <hip/hip_runtime.h>
#include <math.h>

typedef unsigned short u16;
typedef __attribute__((ext_vector_type(4))) float f32x4;
typedef __attribute__((ext_vector_type(8))) __bf16 bf16x8;
typedef __attribute__((ext_vector_type(8))) u16 u16x8;
typedef __attribute__((ext_vector_type(4))) u16 u16x4;

__device__ __forceinline__ float bf2f(u16 v) {
    unsigned int u = ((unsigned int)v) << 16;
    return __builtin_bit_cast(float, u);
}
__device__ __forceinline__ u16 f2bf(float f) {
    unsigned int x = __builtin_bit_cast(unsigned int, f);
    x += 0x7fffu + ((x >> 16) & 1u);   // RNE
    return (u16)(x >> 16);
}

__device__ __forceinline__ void load_lds16(const u16* g, u16* l) {
    __builtin_amdgcn_global_load_lds((const __attribute__((address_space(1))) void*)g,
                                     (__attribute__((address_space(3))) void*)l, 16, 0, 0);
}

#define WAIT_VM(N) asm volatile("s_waitcnt vmcnt(" #N ")" ::: "memory")
#define MFMA16(d, x, y) d = __builtin_amdgcn_mfma_f32_16x16x32_bf16(x, y, d, 0, 0, 0)
// Raw s_barrier bracketed so the compiler cannot move loads/stores across it.
#define BAR() do { __builtin_amdgcn_sched_barrier(0); asm volatile("" ::: "memory"); \
                   __builtin_amdgcn_s_barrier();      asm volatile("" ::: "memory"); \
                   __builtin_amdgcn_sched_barrier(0); } while (0)

// ---------------------------------------------------------------------------
// f32 -> bf16 weight conversion
// ---------------------------------------------------------------------------
__global__ __launch_bounds__(256) void cvt_kernel(const float* __restrict__ in,
                                                  u16* __restrict__ out, int n)
{
    const int i = (blockIdx.x * 256 + threadIdx.x) * 4;
    if (i >= n) return;
    const float4 f = *(const float4*)(in + i);
    u16x4 o;
    o[0] = f2bf(f.x); o[1] = f2bf(f.y); o[2] = f2bf(f.z); o[3] = f2bf(f.w);
    *(u16x4*)(out + i) = o;
}

// ---------------------------------------------------------------------------
// 256x(NFR*64) GEMM, BK=64 double-buffer, ONE barrier per K-tile.
// C[M][N] = epi( A[M][K](bf16, lda) * W[N][K](bf16, ldw)^T + bias )
//
// 8 waves (2M x 4N), per-wave 128x(NFR*16) output, acc[8][NFR]. Per tile:
//   issue ALL fragment ds_reads (24 for NFR=4; 20 for NFR=2)
//   issue ALL next-tile global_load_lds stagings (8 / 6)
//   sched_barrier ; setprio(1)
//   MFMA P0(aL*bL) P1(aL*bH) P2(aH*bL) P3(aH*bH)   // 64 MFMA
//   setprio(0) ; vmcnt(0) ; s_barrier               // ONE barrier/tile
// The compiler inserts its own counted lgkmcnt(12/8/..) before each MFMA
// group, so bH/aH LDS service overlaps P0/P1's MFMAs (round-2 structure had
// 8 barriers + 4 full lgkm drains per tile -> serialized read/MFMA bursts).
// Staging issue->vmcnt(0) distance is the whole tile (~2000+ cy > HBM 900).
//
// LDS 2 x (A 256x64 | B (NFR*64)x64) bf16, rows of 128 B, linear.
// T2 swizzle: (row, 8-u16 seg s) stored at seg s^(row&7) via pre-swizzled
// GLOBAL source col (linear LDS dest) + same XOR on ds_read col.
// NFR=4: B rows permuted n-half-major (contiguous 16 KB half chunks).
//
// EPI 0: qkv scatter (Q/K direct; Vt via LDS transpose). EPI 1: + residual
// (RES=1 f32, RES=2 bf16). EPI 2: exact GELU. OF32: O0 is float*.
// ---------------------------------------------------------------------------
template<int EPI, int RES, bool OF32, int NFR>
__global__ __launch_bounds__(512, 2) void gemm256(
    const u16* __restrict__ A, const u16* __restrict__ W,
    const float* __restrict__ bias,
    const float* __restrict__ resf, const u16* __restrict__ resb,
    void* __restrict__ O0v, u16* __restrict__ O1, u16* __restrict__ O2,
    int M, int N, int K, int lda, int ldw, int mbase)
{
    constexpr int BBASE = 16384;                 // B LDS base (u16)
    constexpr int BUFU  = 16384 + NFR * 4096;    // u16 per double-buffer half
    __shared__ u16 S[2 * BUFU];
    const int tid  = threadIdx.x;
    const int w    = tid >> 6;
    const int l    = tid & 63;
    const int colq = l & 15;
    const int quad = l >> 4;
    const int w3   = w & 3;
    const int wm   = (w >> 2) * 128;      // wave M offset
    const int wn   = w3 * (NFR * 16);     // wave N offset

    // T1: XCD-aware bijective block swizzle (all launches have nwg % 8 == 0)
    const int nX  = (int)gridDim.x;
    const int nwg = nX * (int)gridDim.y;
    const int did = (int)blockIdx.y * nX + (int)blockIdx.x;
    const int q8  = nwg >> 3;
    const int wg  = (nwg & 7) ? did : ((did & 7) * q8 + (did >> 3));
    const int bm  = wg / nX;
    const int bn  = wg - bm * nX;
    const int m0  = bm * 256, n0 = bn * (NFR * 64);

    // -------- staging descriptors ------------------------------------------
    const int rw   = l >> 3;                      // row within 8-row group
    const int sseg = ((l & 7) ^ rw) * 8;          // pre-swizzled global col (u16)
    const u16* gA[2][2];
    const u16* gB[2][2];
#pragma unroll
    for (int h = 0; h < 2; ++h)
#pragma unroll
        for (int j = 0; j < 2; ++j) {
            const int rr = w * 16 + j * 8 + rw;   // LDS row within half (0..127)
            gA[h][j] = A + (size_t)(m0 + h * 128 + rr) * lda + sseg;
            if constexpr (NFR == 4) {
                const int nl = (rr >> 5) * 64 + (h * 2 + ((rr >> 4) & 1)) * 16 + (rr & 15);
                gB[h][j] = W + (size_t)(n0 + nl) * ldw + sseg;
            } else if (h == 0) {
                gB[0][j] = W + (size_t)(n0 + rr) * ldw + sseg;
            }
        }
    const int lw = w * 1024;                      // LDS stage base per wave (u16)

    // -------- fragment read cols (swizzled, u16 units) ---------------------
    const int c0 = (quad * 8) ^ ((colq & 7) << 3);   // kstep0
    const int c1 = c0 ^ 32;                          // kstep1

    f32x4 acc[8][NFR] = {};

    // -------- prologue: stage tile 0, full drain ---------------------------
#pragma unroll
    for (int h = 0; h < 2; ++h)
#pragma unroll
        for (int j = 0; j < 2; ++j)
            load_lds16(gA[h][j], S + h * 8192 + lw + j * 512);
    load_lds16(gB[0][0], S + BBASE + lw);
    load_lds16(gB[0][1], S + BBASE + lw + 512);
    if constexpr (NFR == 4) {
        load_lds16(gB[1][0], S + BBASE + 8192 + lw);
        load_lds16(gB[1][1], S + BBASE + 8192 + lw + 512);
    }
    WAIT_VM(0);
    BAR();

    const int NT = K >> 6;
    for (int t = 0; t < NT; ++t) {
        u16* Sc = S + (t & 1) * BUFU;
        u16* Sn = S + ((t + 1) & 1) * BUFU;
        const int  kk = (t + 1) << 6;
        const bool pf = (t + 1) < NT;

        if constexpr (NFR == 4) {
            bf16x8 aL[4][2], aH[4][2], bL[2][2], bH[2][2];
            // ---- issue ALL fragment reads up front ----
#pragma unroll
            for (int m = 0; m < 4; ++m) {
                const int rb = (wm + m * 16 + colq) * 64;
                aL[m][0] = *(const bf16x8*)(Sc + rb + c0);
                aL[m][1] = *(const bf16x8*)(Sc + rb + c1);
            }
#pragma unroll
            for (int n = 0; n < 2; ++n) {
                const int rb = BBASE + (w3 * 32 + n * 16 + colq) * 64;
                bL[n][0] = *(const bf16x8*)(Sc + rb + c0);
                bL[n][1] = *(const bf16x8*)(Sc + rb + c1);
            }
#pragma unroll
            for (int n = 0; n < 2; ++n) {
                const int rb = BBASE + 8192 + (w3 * 32 + n * 16 + colq) * 64;
                bH[n][0] = *(const bf16x8*)(Sc + rb + c0);
                bH[n][1] = *(const bf16x8*)(Sc + rb + c1);
            }
#pragma unroll
            for (int m = 0; m < 4; ++m) {
                const int rb = (wm + 64 + m * 16 + colq) * 64;
                aH[m][0] = *(const bf16x8*)(Sc + rb + c0);
                aH[m][1] = *(const bf16x8*)(Sc + rb + c1);
            }
            // ---- issue ALL next-tile stagings ----
            if (pf) {
#pragma unroll
                for (int h = 0; h < 2; ++h)
#pragma unroll
                    for (int j = 0; j < 2; ++j)
                        load_lds16(gA[h][j] + kk, Sn + h * 8192 + lw + j * 512);
                load_lds16(gB[0][0] + kk, Sn + BBASE + lw);
                load_lds16(gB[0][1] + kk, Sn + BBASE + lw + 512);
                load_lds16(gB[1][0] + kk, Sn + BBASE + 8192 + lw);
                load_lds16(gB[1][1] + kk, Sn + BBASE + 8192 + lw + 512);
            }
            __builtin_amdgcn_sched_barrier(0);
            __builtin_amdgcn_s_setprio(1);
            // P0: aL x bL (ready first -> compiler waits lgkmcnt(12))
#pragma unroll
            for (int m = 0; m < 4; ++m)
#pragma unroll
                for (int n = 0; n < 2; ++n) {
                    MFMA16(acc[m][n], aL[m][0], bL[n][0]);
                    MFMA16(acc[m][n], aL[m][1], bL[n][1]);
                }
            // P1: aL x bH (bH service overlapped P0)
#pragma unroll
            for (int m = 0; m < 4; ++m)
#pragma unroll
                for (int n = 0; n < 2; ++n) {
                    MFMA16(acc[m][2 + n], aL[m][0], bH[n][0]);
                    MFMA16(acc[m][2 + n], aL[m][1], bH[n][1]);
                }
            // P2: aH x bL (aH service overlapped P0/P1)
#pragma unroll
            for (int m = 0; m < 4; ++m)
#pragma unroll
                for (int n = 0; n < 2; ++n) {
                    MFMA16(acc[4 + m][n], aH[m][0], bL[n][0]);
                    MFMA16(acc[4 + m][n], aH[m][1], bL[n][1]);
                }
            // P3: aH x bH
#pragma unroll
            for (int m = 0; m < 4; ++m)
#pragma unroll
                for (int n = 0; n < 2; ++n) {
                    MFMA16(acc[4 + m][2 + n], aH[m][0], bH[n][0]);
                    MFMA16(acc[4 + m][2 + n], aH[m][1], bH[n][1]);
                }
            __builtin_amdgcn_s_setprio(0);
        } else {
            bf16x8 aL[4][2], aH[4][2], bb[2][2];
#pragma unroll
            for (int m = 0; m < 4; ++m) {
                const int rb = (wm + m * 16 + colq) * 64;
                aL[m][0] = *(const bf16x8*)(Sc + rb + c0);
                aL[m][1] = *(const bf16x8*)(Sc + rb + c1);
            }
#pragma unroll
            for (int n = 0; n < 2; ++n) {
                const int rb = BBASE + (w3 * 32 + n * 16 + colq) * 64;
                bb[n][0] = *(const bf16x8*)(Sc + rb + c0);
                bb[n][1] = *(const bf16x8*)(Sc + rb + c1);
            }
#pragma unroll
            for (int m = 0; m < 4; ++m) {
                const int rb = (wm + 64 + m * 16 + colq) * 64;
                aH[m][0] = *(const bf16x8*)(Sc + rb + c0);
                aH[m][1] = *(const bf16x8*)(Sc + rb + c1);
            }
            if (pf) {
#pragma unroll
                for (int h = 0; h < 2; ++h)
#pragma unroll
                    for (int j = 0; j < 2; ++j)
                        load_lds16(gA[h][j] + kk, Sn + h * 8192 + lw + j * 512);
                load_lds16(gB[0][0] + kk, Sn + BBASE + lw);
                load_lds16(gB[0][1] + kk, Sn + BBASE + lw + 512);
            }
            __builtin_amdgcn_sched_barrier(0);
            __builtin_amdgcn_s_setprio(1);
#pragma unroll
            for (int m = 0; m < 4; ++m)
#pragma unroll
                for (int n = 0; n < 2; ++n) {
                    MFMA16(acc[m][n], aL[m][0], bb[n][0]);
                    MFMA16(acc[m][n], aL[m][1], bb[n][1]);
                }
#pragma unroll
            for (int m = 0; m < 4; ++m)
#pragma unroll
                for (int n = 0; n < 2; ++n) {
                    MFMA16(acc[4 + m][n], aH[m][0], bb[n][0]);
                    MFMA16(acc[4 + m][n], aH[m][1], bb[n][1]);
                }
            __builtin_amdgcn_s_setprio(0);
        }
        if (pf) { WAIT_VM(0); }
        BAR();
    }

    // -------- epilogue ------------------------------------------------------
    // C/D layout (m89): row = quad*4+i, col = colq within each 16x16 frag.
    if constexpr (EPI == 0) {
        if (n0 >= 2048) {
            // Vt block: LDS transpose -> coalesced stores along t.
            __syncthreads();
#pragma unroll
            for (int nf = 0; nf < NFR; ++nf) {
                const int cl = wn + nf * 16 + colq;
                const float bz = bias[n0 + cl];
                const int swz = (cl & 7) << 3;
#pragma unroll
                for (int mf = 0; mf < 8; ++mf) {
                    const int rb = wm + mf * 16 + quad * 4;
                    u16x4 pk;
#pragma unroll
                    for (int i = 0; i < 4; ++i) pk[i] = f2bf(acc[mf][nf][i] + bz);
                    *(u16x4*)(S + cl * 256 + (rb ^ swz)) = pk;
                }
            }
            __syncthreads();
            const int cl   = tid >> 1;
            const int c    = n0 + cl;
            const int head = (c >> 6) & 15;
            const int d    = c & 63;
            const int rg0  = mbase + m0;
            const int bh   = (rg0 >> 12) * 16 + head;
            const int half = tid & 1;
            const int swz  = (cl & 7) << 3;
            u16* op = O2 + ((size_t)bh * 64 + d) * 4096 + (rg0 & 4095) + half * 128;
#pragma unroll
            for (int j = 0; j < 16; ++j) {
                const int r0 = half * 128 + j * 8;
                *(u16x8*)(op + j * 8) = *(const u16x8*)(S + cl * 256 + (r0 ^ swz));
            }
            return;
        }
    }
#pragma unroll
    for (int nf = 0; nf < NFR; ++nf) {
        const int c = n0 + wn + nf * 16 + colq;
        const float bz = bias ? bias[c] : 0.f;
#pragma unroll
        for (int mf = 0; mf < 8; ++mf) {
#pragma unroll
            for (int i = 0; i < 4; ++i) {
                const int r = m0 + wm + mf * 16 + quad * 4 + i;
                float v = acc[mf][nf][i] + bz;
                if constexpr (EPI == 0) {
                    const int head = (c >> 6) & 15;
                    const int d    = c & 63;
                    const int rg   = mbase + r;
                    const int tt   = rg & 4095;
                    const int bh   = (rg >> 12) * 16 + head;
                    const u16 val = f2bf(v);
                    if (c < 1024) ((u16*)O0v)[((size_t)bh * 4096 + tt) * 64 + d] = val; // Q
                    else          O1[((size_t)bh * 4096 + tt) * 64 + d] = val;          // K
                } else {
                    const size_t idx = (size_t)r * N + c;
                    if constexpr (RES == 1) v += resf[idx];
                    if constexpr (RES == 2) v += bf2f(resb[idx]);
                    if constexpr (EPI == 2) v = 0.5f * v * (1.0f + erff(v * 0.70710678118654752f));
                    if constexpr (OF32) ((float*)O0v)[idx] = v;
                    else                ((u16*)O0v)[idx] = f2bf(v);
                }
            }
        }
    }
}

// ---------------------------------------------------------------------------
// LayerNorm: one wave per row of 1024. F32IN: x is f32 (LN1); else bf16 (LN2).
// ---------------------------------------------------------------------------
template<bool F32IN>
__global__ __launch_bounds__(256) void ln_kernel(
    const void* __restrict__ xin, const float* __restrict__ w,
    const float* __restrict__ b, u16* __restrict__ out)
{
    const int wave = threadIdx.x >> 6, lane = threadIdx.x & 63;
    const size_t row = (size_t)blockIdx.x * 4 + wave;
    float v[16];
    if constexpr (F32IN) {
        const float* xr = (const float*)xin + row * 1024 + lane * 16;
#pragma unroll
        for (int j = 0; j < 4; ++j) {
            const float4 f = *(const float4*)(xr + j * 4);
            v[j * 4 + 0] = f.x; v[j * 4 + 1] = f.y; v[j * 4 + 2] = f.z; v[j * 4 + 3] = f.w;
        }
    } else {
        const u16* xr = (const u16*)xin + row * 1024 + lane * 16;
        u16x8 xa = *(const u16x8*)xr;
        u16x8 xb = *(const u16x8*)(xr + 8);
#pragma unroll
        for (int i = 0; i < 8; ++i) { v[i] = bf2f(xa[i]); v[8 + i] = bf2f(xb[i]); }
    }
    float s = 0.f, s2 = 0.f;
#pragma unroll
    for (int i = 0; i < 16; ++i) { s += v[i]; s2 += v[i] * v[i]; }
#pragma unroll
    for (int m = 32; m >= 1; m >>= 1) { s += __shfl_xor(s, m, 64); s2 += __shfl_xor(s2, m, 64); }
    const float mu  = s * (1.0f / 1024.0f);
    const float var = s2 * (1.0f / 1024.0f) - mu * mu;
    const float rs  = rsqrtf(var + 1e-5f);
    const float* wp = w + lane * 16;
    const float* bp = b + lane * 16;
    u16x8 oa, ob;
#pragma unroll
    for (int i = 0; i < 8; ++i) {
        oa[i] = f2bf((v[i]     - mu) * rs * wp[i]     + bp[i]);
        ob[i] = f2bf((v[8 + i] - mu) * rs * wp[8 + i] + bp[8 + i]);
    }
    u16* orow = out + row * 1024 + lane * 16;
    *(u16x8*)orow       = oa;
    *(u16x8*)(orow + 8) = ob;
}

// ---------------------------------------------------------------------------
// Local attention, flash-style over 2 key-chunks of 192.
// Round-2 body (conditional loads, launch_bounds(256,4): 56 VGPR, no spills)
// + exp2f folded scale + T5 setprio around MFMA clusters.
// ---------------------------------------------------------------------------
__global__ __launch_bounds__(256, 4) void attn_kernel(
    const u16* __restrict__ Q, const u16* __restrict__ Kb,
    const u16* __restrict__ Vt, u16* __restrict__ out)
{
    __shared__ u16 Ps[4][16 * 200];
    const int tid  = threadIdx.x;
    const int wave = tid >> 6;
    const int lane = tid & 63;
    const int colq = lane & 15;
    const int quad = lane >> 4;
    const float C2 = 0.18033688011112042f;   // 0.125 * log2(e)

    const int f   = blockIdx.x;            // 0..4095
    const int xcd = f & 7;
    const int s8  = f >> 3;                // 0..511
    const int bh  = s8 >> 3;               // 0..63
    const int tb  = (s8 & 7) + 8 * xcd;    // 0..63
    const int qrow0 = tb * 64 + wave * 16;
    const int nb    = tb >> 1;
    const int key0  = nb * 128 - 128;
    const int nt_lo = (nb == 0) ? 8 : 0;
    const int nt_hi = (nb == 31) ? 16 : 24;

    const u16* qp = Q + ((size_t)bh * 4096 + qrow0 + colq) * 64 + quad * 8;
    bf16x8 aq0 = *(const bf16x8*)qp;
    bf16x8 aq1 = *(const bf16x8*)(qp + 32);

    float m_i[4], l_i[4];
    f32x4 o[4] = {};
#pragma unroll
    for (int i = 0; i < 4; ++i) { m_i[i] = -3.0e38f; l_i[i] = 0.f; }

    u16* Psw = &Ps[wave][0];

#pragma unroll
    for (int c = 0; c < 2; ++c) {
        const int lo = (c == 0) ? nt_lo : 12;
        const int hi = (c == 0) ? ((nt_hi < 12) ? nt_hi : 12) : nt_hi;

        f32x4 sc[12];
#pragma unroll
        for (int j = 0; j < 12; ++j) sc[j] = (f32x4){0.f, 0.f, 0.f, 0.f};
#pragma unroll
        for (int j = 0; j < 12; ++j) {
            const int nt = c * 12 + j;
            if (nt >= lo && nt < hi) {
                const u16* kp = Kb + ((size_t)bh * 4096 + key0 + nt * 16 + colq) * 64 + quad * 8;
                bf16x8 b0 = *(const bf16x8*)kp;
                bf16x8 b1 = *(const bf16x8*)(kp + 32);
                f32x4 z = {0.f, 0.f, 0.f, 0.f};
                __builtin_amdgcn_s_setprio(1);
                z = __builtin_amdgcn_mfma_f32_16x16x32_bf16(aq0, b0, z, 0, 0, 0);
                z = __builtin_amdgcn_mfma_f32_16x16x32_bf16(aq1, b1, z, 0, 0, 0);
                __builtin_amdgcn_s_setprio(0);
                sc[j] = z;
            }
        }
        float mc[4];
#pragma unroll
        for (int i = 0; i < 4; ++i) mc[i] = -3.0e38f;
#pragma unroll
        for (int j = 0; j < 12; ++j) {
            const int nt = c * 12 + j;
            if (nt >= lo && nt < hi)
#pragma unroll
                for (int i = 0; i < 4; ++i) mc[i] = fmaxf(mc[i], sc[j][i]);
        }
#pragma unroll
        for (int i = 0; i < 4; ++i)
#pragma unroll
            for (int m = 8; m >= 1; m >>= 1) mc[i] = fmaxf(mc[i], __shfl_xor(mc[i], m, 64));
        float a_i[4], psum[4];
#pragma unroll
        for (int i = 0; i < 4; ++i) {
            const float mn = fmaxf(m_i[i], mc[i]);
            a_i[i] = exp2f((m_i[i] - mn) * C2);
            m_i[i] = mn;
            psum[i] = 0.f;
        }
#pragma unroll
        for (int j = 0; j < 12; ++j) {
            const int nt = c * 12 + j;
            if (nt >= lo && nt < hi) {
#pragma unroll
                for (int i = 0; i < 4; ++i) {
                    const float p = exp2f((sc[j][i] - m_i[i]) * C2);
                    psum[i] += p;
                    Psw[(quad * 4 + i) * 200 + j * 16 + colq] = f2bf(p);
                }
            }
        }
#pragma unroll
        for (int i = 0; i < 4; ++i)
#pragma unroll
            for (int m = 8; m >= 1; m >>= 1) psum[i] += __shfl_xor(psum[i], m, 64);
#pragma unroll
        for (int i = 0; i < 4; ++i) l_i[i] = l_i[i] * a_i[i] + psum[i];
#pragma unroll
        for (int dt = 0; dt < 4; ++dt)
#pragma unroll
            for (int i = 0; i < 4; ++i) o[dt][i] *= a_i[i];
        const int klo = (lo - c * 12) >> 1;
        const int khi = (hi - c * 12) >> 1;
#pragma unroll
        for (int k6 = 0; k6 < 6; ++k6) {
            if (k6 >= klo && k6 < khi) {
                bf16x8 ap = *(const bf16x8*)(Psw + colq * 200 + k6 * 32 + quad * 8);
                const int kkk = key0 + (c * 6 + k6) * 32 + quad * 8;
                __builtin_amdgcn_s_setprio(1);
#pragma unroll
                for (int dt = 0; dt < 4; ++dt) {
                    const u16* vp = Vt + ((size_t)bh * 64 + dt * 16 + colq) * 4096 + kkk;
                    bf16x8 bv = *(const bf16x8*)vp;
                    o[dt] = __builtin_amdgcn_mfma_f32_16x16x32_bf16(ap, bv, o[dt], 0, 0, 0);
                }
                __builtin_amdgcn_s_setprio(0);
            }
        }
    }

    const int bb = bh >> 4, hh = bh & 15;
#pragma unroll
    for (int i = 0; i < 4; ++i) {
        const float inv = 1.0f / fmaxf(l_i[i], 1e-20f);
        const int t = qrow0 + quad * 4 + i;
        u16* op = out + ((size_t)(bb * 4096 + t)) * 1024 + hh * 64;
#pragma unroll
        for (int dt = 0; dt < 4; ++dt) op[dt * 16 + colq] = f2bf(o[dt][i] * inv);
    }
}

// ---------------------------------------------------------------------------
extern "C" void kernel_launch(void* const* d_in, const int* in_sizes, int n_in,
                              void* d_out, int out_size, void* d_ws, size_t ws_size,
                              hipStream_t stream)
{
    const float* x      = (const float*)d_in[0];
    const float* ln1_w  = (const float*)d_in[1];
    const float* ln1_b  = (const float*)d_in[2];
    const float* qkv_w  = (const float*)d_in[3];
    const float* qkv_b  = (const float*)d_in[4];
    const float* proj_w = (const float*)d_in[5];
    const float* proj_b = (const float*)d_in[6];
    const float* ln2_w  = (const float*)d_in[7];
    const float* ln2_b  = (const float*)d_in[8];
    const float* fc1_w  = (const float*)d_in[9];
    const float* fc1_b  = (const float*)d_in[10];
    const float* fc2_w  = (const float*)d_in[11];
    const float* fc2_b  = (const float*)d_in[12];
    float* outp = (float*)d_out;

    if (ws_size < 134217728u) return;
    char* ws = (char*)d_ws;
    u16* R0 = (u16*)(ws);               // bf16 weights (25.2 MB)
    u16* R1 = (u16*)(ws + 33554432);    // Q  -> x2 (bf16)
    u16* R2 = (u16*)(ws + 67108864);    // K  -> h lower half
    u16* R3 = (u16*)(ws + 100663296);   // Vt -> h upper half
    // d_out scratch: xn @ [0:33.5M), attn/yn @ [33.5M:67M).
    u16* xnc    = (u16*)d_out;
    u16* attn_o = (u16*)((char*)d_out + 33554432);

    u16* qkvwb  = R0;
    u16* projwb = R0 + 3145728;
    u16* fc1wb  = R0 + 4194304;
    u16* fc2wb  = R0 + 8388608;
    u16* Qb = R1, *Kb = R2, *Vtb = R3;
    u16* x2 = R1;                       // Q dead after attn
    u16* yn = attn_o;                   // attn_o dead after proj
    u16* hb = R2;                       // K,Vt dead after attn: 67 MB contiguous

    // 1. weights f32 -> bf16
    cvt_kernel<<<3072, 256, 0, stream>>>(qkv_w, qkvwb, 3145728);
    cvt_kernel<<<1024, 256, 0, stream>>>(proj_w, projwb, 1048576);
    cvt_kernel<<<4096, 256, 0, stream>>>(fc1_w, fc1wb, 4194304);
    cvt_kernel<<<4096, 256, 0, stream>>>(fc2_w, fc2wb, 4194304);
    // 2. LN1: x -> xn
    ln_kernel<true><<<4096, 256, 0, stream>>>(x, ln1_w, ln1_b, xnc);
    // 3. qkv GEMM + scatter (768 blocks)
    gemm256<0, 0, false, 4><<<dim3(12, 64), 512, 0, stream>>>(
        xnc, qkvwb, qkv_b, nullptr, nullptr, Qb, Kb, Vtb,
        16384, 3072, 1024, 1024, 1024, 0);
    // 4. local attention -> attn_o
    attn_kernel<<<4096, 256, 0, stream>>>(Qb, Kb, Vtb, attn_o);
    // 5. proj + residual(x, f32) -> x2 bf16 (256 blocks)
    gemm256<1, 1, false, 4><<<dim3(4, 64), 512, 0, stream>>>(
        attn_o, projwb, proj_b, x, nullptr, x2, nullptr, nullptr,
        16384, 1024, 1024, 1024, 1024, 0);
    // 6. LN2: x2 -> yn
    ln_kernel<false><<<4096, 256, 0, stream>>>(x2, ln2_w, ln2_b, yn);
    // 7. FFN in 2 M-chunks of 8192 rows; h (67 MB) in R2+R3.
    //    fc1: 512 blocks (BN=256). fc2: BN=128 variant -> 8x32 = 256 blocks.
    for (int ci = 0; ci < 2; ++ci) {
        const size_t off = (size_t)ci * 8192 * 1024;
        gemm256<2, 0, false, 4><<<dim3(16, 32), 512, 0, stream>>>(
            yn + off, fc1wb, fc1_b, nullptr, nullptr, hb, nullptr, nullptr,
            8192, 4096, 1024, 1024, 1024, 0);
        gemm256<1, 2, true, 2><<<dim3(8, 32), 512, 0, stream>>>(
            hb, fc2wb, fc2_b, nullptr, x2 + off, outp + off, nullptr, nullptr,
            8192, 1024, 4096, 4096, 4096, 0);
    }
}

// Round 7
// 951.565 us; speedup vs baseline: 1.1756x; 1.0016x over previous
//
#include <hip/hip_runtime.h>
#include <math.h>

typedef unsigned short u16;
typedef __attribute__((ext_vector_type(4))) float f32x4;
typedef __attribute__((ext_vector_type(8))) __bf16 bf16x8;
typedef __attribute__((ext_vector_type(8))) u16 u16x8;
typedef __attribute__((ext_vector_type(4))) u16 u16x4;

__device__ __forceinline__ float bf2f(u16 v) {
    unsigned int u = ((unsigned int)v) << 16;
    return __builtin_bit_cast(float, u);
}
__device__ __forceinline__ u16 f2bf(float f) {
    unsigned int x = __builtin_bit_cast(unsigned int, f);
    x += 0x7fffu + ((x >> 16) & 1u);   // RNE
    return (u16)(x >> 16);
}

__device__ __forceinline__ void load_lds16(const u16* g, u16* l) {
    __builtin_amdgcn_global_load_lds((const __attribute__((address_space(1))) void*)g,
                                     (__attribute__((address_space(3))) void*)l, 16, 0, 0);
}

#define WAIT_VM(N) asm volatile("s_waitcnt vmcnt(" #N ")" ::: "memory")
#define MFMA16(d, x, y) d = __builtin_amdgcn_mfma_f32_16x16x32_bf16(x, y, d, 0, 0, 0)
// Raw s_barrier bracketed so the compiler cannot move loads/stores across it.
#define BAR() do { __builtin_amdgcn_sched_barrier(0); asm volatile("" ::: "memory"); \
                   __builtin_amdgcn_s_barrier();      asm volatile("" ::: "memory"); \
                   __builtin_amdgcn_sched_barrier(0); } while (0)

// ---------------------------------------------------------------------------
// f32 -> bf16 weight conversion
// ---------------------------------------------------------------------------
__global__ __launch_bounds__(256) void cvt_kernel(const float* __restrict__ in,
                                                  u16* __restrict__ out, int n)
{
    const int i = (blockIdx.x * 256 + threadIdx.x) * 4;
    if (i >= n) return;
    const float4 f = *(const float4*)(in + i);
    u16x4 o;
    o[0] = f2bf(f.x); o[1] = f2bf(f.y); o[2] = f2bf(f.z); o[3] = f2bf(f.w);
    *(u16x4*)(out + i) = o;
}

// ---------------------------------------------------------------------------
// 256x(NFR*64) GEMM, BK=64 double-buffer, ONE barrier per K-tile.
// (unchanged from round 6 — the verified winner)
// ---------------------------------------------------------------------------
template<int EPI, int RES, bool OF32, int NFR>
__global__ __launch_bounds__(512, 2) void gemm256(
    const u16* __restrict__ A, const u16* __restrict__ W,
    const float* __restrict__ bias,
    const float* __restrict__ resf, const u16* __restrict__ resb,
    void* __restrict__ O0v, u16* __restrict__ O1, u16* __restrict__ O2,
    int M, int N, int K, int lda, int ldw, int mbase)
{
    constexpr int BBASE = 16384;                 // B LDS base (u16)
    constexpr int BUFU  = 16384 + NFR * 4096;    // u16 per double-buffer half
    __shared__ u16 S[2 * BUFU];
    const int tid  = threadIdx.x;
    const int w    = tid >> 6;
    const int l    = tid & 63;
    const int colq = l & 15;
    const int quad = l >> 4;
    const int w3   = w & 3;
    const int wm   = (w >> 2) * 128;      // wave M offset
    const int wn   = w3 * (NFR * 16);     // wave N offset

    // T1: XCD-aware bijective block swizzle (all launches have nwg % 8 == 0)
    const int nX  = (int)gridDim.x;
    const int nwg = nX * (int)gridDim.y;
    const int did = (int)blockIdx.y * nX + (int)blockIdx.x;
    const int q8  = nwg >> 3;
    const int wg  = (nwg & 7) ? did : ((did & 7) * q8 + (did >> 3));
    const int bm  = wg / nX;
    const int bn  = wg - bm * nX;
    const int m0  = bm * 256, n0 = bn * (NFR * 64);

    // -------- staging descriptors ------------------------------------------
    const int rw   = l >> 3;                      // row within 8-row group
    const int sseg = ((l & 7) ^ rw) * 8;          // pre-swizzled global col (u16)
    const u16* gA[2][2];
    const u16* gB[2][2];
#pragma unroll
    for (int h = 0; h < 2; ++h)
#pragma unroll
        for (int j = 0; j < 2; ++j) {
            const int rr = w * 16 + j * 8 + rw;   // LDS row within half (0..127)
            gA[h][j] = A + (size_t)(m0 + h * 128 + rr) * lda + sseg;
            if constexpr (NFR == 4) {
                const int nl = (rr >> 5) * 64 + (h * 2 + ((rr >> 4) & 1)) * 16 + (rr & 15);
                gB[h][j] = W + (size_t)(n0 + nl) * ldw + sseg;
            } else if (h == 0) {
                gB[0][j] = W + (size_t)(n0 + rr) * ldw + sseg;
            }
        }
    const int lw = w * 1024;                      // LDS stage base per wave (u16)

    // -------- fragment read cols (swizzled, u16 units) ---------------------
    const int c0 = (quad * 8) ^ ((colq & 7) << 3);   // kstep0
    const int c1 = c0 ^ 32;                          // kstep1

    f32x4 acc[8][NFR] = {};

    // -------- prologue: stage tile 0, full drain ---------------------------
#pragma unroll
    for (int h = 0; h < 2; ++h)
#pragma unroll
        for (int j = 0; j < 2; ++j)
            load_lds16(gA[h][j], S + h * 8192 + lw + j * 512);
    load_lds16(gB[0][0], S + BBASE + lw);
    load_lds16(gB[0][1], S + BBASE + lw + 512);
    if constexpr (NFR == 4) {
        load_lds16(gB[1][0], S + BBASE + 8192 + lw);
        load_lds16(gB[1][1], S + BBASE + 8192 + lw + 512);
    }
    WAIT_VM(0);
    BAR();

    const int NT = K >> 6;
    for (int t = 0; t < NT; ++t) {
        u16* Sc = S + (t & 1) * BUFU;
        u16* Sn = S + ((t + 1) & 1) * BUFU;
        const int  kk = (t + 1) << 6;
        const bool pf = (t + 1) < NT;

        if constexpr (NFR == 4) {
            bf16x8 aL[4][2], aH[4][2], bL[2][2], bH[2][2];
            // ---- issue ALL fragment reads up front ----
#pragma unroll
            for (int m = 0; m < 4; ++m) {
                const int rb = (wm + m * 16 + colq) * 64;
                aL[m][0] = *(const bf16x8*)(Sc + rb + c0);
                aL[m][1] = *(const bf16x8*)(Sc + rb + c1);
            }
#pragma unroll
            for (int n = 0; n < 2; ++n) {
                const int rb = BBASE + (w3 * 32 + n * 16 + colq) * 64;
                bL[n][0] = *(const bf16x8*)(Sc + rb + c0);
                bL[n][1] = *(const bf16x8*)(Sc + rb + c1);
            }
#pragma unroll
            for (int n = 0; n < 2; ++n) {
                const int rb = BBASE + 8192 + (w3 * 32 + n * 16 + colq) * 64;
                bH[n][0] = *(const bf16x8*)(Sc + rb + c0);
                bH[n][1] = *(const bf16x8*)(Sc + rb + c1);
            }
#pragma unroll
            for (int m = 0; m < 4; ++m) {
                const int rb = (wm + 64 + m * 16 + colq) * 64;
                aH[m][0] = *(const bf16x8*)(Sc + rb + c0);
                aH[m][1] = *(const bf16x8*)(Sc + rb + c1);
            }
            // ---- issue ALL next-tile stagings ----
            if (pf) {
#pragma unroll
                for (int h = 0; h < 2; ++h)
#pragma unroll
                    for (int j = 0; j < 2; ++j)
                        load_lds16(gA[h][j] + kk, Sn + h * 8192 + lw + j * 512);
                load_lds16(gB[0][0] + kk, Sn + BBASE + lw);
                load_lds16(gB[0][1] + kk, Sn + BBASE + lw + 512);
                load_lds16(gB[1][0] + kk, Sn + BBASE + 8192 + lw);
                load_lds16(gB[1][1] + kk, Sn + BBASE + 8192 + lw + 512);
            }
            __builtin_amdgcn_sched_barrier(0);
            __builtin_amdgcn_s_setprio(1);
            // P0: aL x bL
#pragma unroll
            for (int m = 0; m < 4; ++m)
#pragma unroll
                for (int n = 0; n < 2; ++n) {
                    MFMA16(acc[m][n], aL[m][0], bL[n][0]);
                    MFMA16(acc[m][n], aL[m][1], bL[n][1]);
                }
            // P1: aL x bH
#pragma unroll
            for (int m = 0; m < 4; ++m)
#pragma unroll
                for (int n = 0; n < 2; ++n) {
                    MFMA16(acc[m][2 + n], aL[m][0], bH[n][0]);
                    MFMA16(acc[m][2 + n], aL[m][1], bH[n][1]);
                }
            // P2: aH x bL
#pragma unroll
            for (int m = 0; m < 4; ++m)
#pragma unroll
                for (int n = 0; n < 2; ++n) {
                    MFMA16(acc[4 + m][n], aH[m][0], bL[n][0]);
                    MFMA16(acc[4 + m][n], aH[m][1], bL[n][1]);
                }
            // P3: aH x bH
#pragma unroll
            for (int m = 0; m < 4; ++m)
#pragma unroll
                for (int n = 0; n < 2; ++n) {
                    MFMA16(acc[4 + m][2 + n], aH[m][0], bH[n][0]);
                    MFMA16(acc[4 + m][2 + n], aH[m][1], bH[n][1]);
                }
            __builtin_amdgcn_s_setprio(0);
        } else {
            bf16x8 aL[4][2], aH[4][2], bb[2][2];
#pragma unroll
            for (int m = 0; m < 4; ++m) {
                const int rb = (wm + m * 16 + colq) * 64;
                aL[m][0] = *(const bf16x8*)(Sc + rb + c0);
                aL[m][1] = *(const bf16x8*)(Sc + rb + c1);
            }
#pragma unroll
            for (int n = 0; n < 2; ++n) {
                const int rb = BBASE + (w3 * 32 + n * 16 + colq) * 64;
                bb[n][0] = *(const bf16x8*)(Sc + rb + c0);
                bb[n][1] = *(const bf16x8*)(Sc + rb + c1);
            }
#pragma unroll
            for (int m = 0; m < 4; ++m) {
                const int rb = (wm + 64 + m * 16 + colq) * 64;
                aH[m][0] = *(const bf16x8*)(Sc + rb + c0);
                aH[m][1] = *(const bf16x8*)(Sc + rb + c1);
            }
            if (pf) {
#pragma unroll
                for (int h = 0; h < 2; ++h)
#pragma unroll
                    for (int j = 0; j < 2; ++j)
                        load_lds16(gA[h][j] + kk, Sn + h * 8192 + lw + j * 512);
                load_lds16(gB[0][0] + kk, Sn + BBASE + lw);
                load_lds16(gB[0][1] + kk, Sn + BBASE + lw + 512);
            }
            __builtin_amdgcn_sched_barrier(0);
            __builtin_amdgcn_s_setprio(1);
#pragma unroll
            for (int m = 0; m < 4; ++m)
#pragma unroll
                for (int n = 0; n < 2; ++n) {
                    MFMA16(acc[m][n], aL[m][0], bb[n][0]);
                    MFMA16(acc[m][n], aL[m][1], bb[n][1]);
                }
#pragma unroll
            for (int m = 0; m < 4; ++m)
#pragma unroll
                for (int n = 0; n < 2; ++n) {
                    MFMA16(acc[4 + m][n], aH[m][0], bb[n][0]);
                    MFMA16(acc[4 + m][n], aH[m][1], bb[n][1]);
                }
            __builtin_amdgcn_s_setprio(0);
        }
        if (pf) { WAIT_VM(0); }
        BAR();
    }

    // -------- epilogue ------------------------------------------------------
    if constexpr (EPI == 0) {
        if (n0 >= 2048) {
            // Vt block: LDS transpose -> coalesced stores along t.
            __syncthreads();
#pragma unroll
            for (int nf = 0; nf < NFR; ++nf) {
                const int cl = wn + nf * 16 + colq;
                const float bz = bias[n0 + cl];
                const int swz = (cl & 7) << 3;
#pragma unroll
                for (int mf = 0; mf < 8; ++mf) {
                    const int rb = wm + mf * 16 + quad * 4;
                    u16x4 pk;
#pragma unroll
                    for (int i = 0; i < 4; ++i) pk[i] = f2bf(acc[mf][nf][i] + bz);
                    *(u16x4*)(S + cl * 256 + (rb ^ swz)) = pk;
                }
            }
            __syncthreads();
            const int cl   = tid >> 1;
            const int c    = n0 + cl;
            const int head = (c >> 6) & 15;
            const int d    = c & 63;
            const int rg0  = mbase + m0;
            const int bh   = (rg0 >> 12) * 16 + head;
            const int half = tid & 1;
            const int swz  = (cl & 7) << 3;
            u16* op = O2 + ((size_t)bh * 64 + d) * 4096 + (rg0 & 4095) + half * 128;
#pragma unroll
            for (int j = 0; j < 16; ++j) {
                const int r0 = half * 128 + j * 8;
                *(u16x8*)(op + j * 8) = *(const u16x8*)(S + cl * 256 + (r0 ^ swz));
            }
            return;
        }
    }
#pragma unroll
    for (int nf = 0; nf < NFR; ++nf) {
        const int c = n0 + wn + nf * 16 + colq;
        const float bz = bias ? bias[c] : 0.f;
#pragma unroll
        for (int mf = 0; mf < 8; ++mf) {
#pragma unroll
            for (int i = 0; i < 4; ++i) {
                const int r = m0 + wm + mf * 16 + quad * 4 + i;
                float v = acc[mf][nf][i] + bz;
                if constexpr (EPI == 0) {
                    const int head = (c >> 6) & 15;
                    const int d    = c & 63;
                    const int rg   = mbase + r;
                    const int tt   = rg & 4095;
                    const int bh   = (rg >> 12) * 16 + head;
                    const u16 val = f2bf(v);
                    if (c < 1024) ((u16*)O0v)[((size_t)bh * 4096 + tt) * 64 + d] = val; // Q
                    else          O1[((size_t)bh * 4096 + tt) * 64 + d] = val;          // K
                } else {
                    const size_t idx = (size_t)r * N + c;
                    if constexpr (RES == 1) v += resf[idx];
                    if constexpr (RES == 2) v += bf2f(resb[idx]);
                    if constexpr (EPI == 2) v = 0.5f * v * (1.0f + erff(v * 0.70710678118654752f));
                    if constexpr (OF32) ((float*)O0v)[idx] = v;
                    else                ((u16*)O0v)[idx] = f2bf(v);
                }
            }
        }
    }
}

// ---------------------------------------------------------------------------
// LayerNorm: one wave per row of 1024. F32IN: x is f32 (LN1); else bf16 (LN2).
// ---------------------------------------------------------------------------
template<bool F32IN>
__global__ __launch_bounds__(256) void ln_kernel(
    const void* __restrict__ xin, const float* __restrict__ w,
    const float* __restrict__ b, u16* __restrict__ out)
{
    const int wave = threadIdx.x >> 6, lane = threadIdx.x & 63;
    const size_t row = (size_t)blockIdx.x * 4 + wave;
    float v[16];
    if constexpr (F32IN) {
        const float* xr = (const float*)xin + row * 1024 + lane * 16;
#pragma unroll
        for (int j = 0; j < 4; ++j) {
            const float4 f = *(const float4*)(xr + j * 4);
            v[j * 4 + 0] = f.x; v[j * 4 + 1] = f.y; v[j * 4 + 2] = f.z; v[j * 4 + 3] = f.w;
        }
    } else {
        const u16* xr = (const u16*)xin + row * 1024 + lane * 16;
        u16x8 xa = *(const u16x8*)xr;
        u16x8 xb = *(const u16x8*)(xr + 8);
#pragma unroll
        for (int i = 0; i < 8; ++i) { v[i] = bf2f(xa[i]); v[8 + i] = bf2f(xb[i]); }
    }
    float s = 0.f, s2 = 0.f;
#pragma unroll
    for (int i = 0; i < 16; ++i) { s += v[i]; s2 += v[i] * v[i]; }
#pragma unroll
    for (int m = 32; m >= 1; m >>= 1) { s += __shfl_xor(s, m, 64); s2 += __shfl_xor(s2, m, 64); }
    const float mu  = s * (1.0f / 1024.0f);
    const float var = s2 * (1.0f / 1024.0f) - mu * mu;
    const float rs  = rsqrtf(var + 1e-5f);
    const float* wp = w + lane * 16;
    const float* bp = b + lane * 16;
    u16x8 oa, ob;
#pragma unroll
    for (int i = 0; i < 8; ++i) {
        oa[i] = f2bf((v[i]     - mu) * rs * wp[i]     + bp[i]);
        ob[i] = f2bf((v[8 + i] - mu) * rs * wp[8 + i] + bp[8 + i]);
    }
    u16* orow = out + row * 1024 + lane * 16;
    *(u16x8*)orow       = oa;
    *(u16x8*)(orow + 8) = ob;
}

// ---------------------------------------------------------------------------
// Local attention, flash-style over 2 key-chunks of 192.
// template<EDGE>: interior blocks (60/64) take a BRANCH-FREE path — loads
// unconditional, no masks -> compiler batches loads with counted vmcnt
// (deep MLP). Edge blocks (nb==0||31) keep the proven masked path.
// launch_bounds(256,4): the (256,6) variants spilled (r3/r5: VGPR->40,
// WRITE +100-230MB); keep the 128-VGPR regime.
// ---------------------------------------------------------------------------
template<bool EDGE>
__device__ __forceinline__ void attn_body(
    const u16* __restrict__ Q, const u16* __restrict__ Kb,
    const u16* __restrict__ Vt, u16* __restrict__ out,
    int bh, int qrow0, int key0, int nt_lo, int nt_hi,
    u16* Psw, int colq, int quad)
{
    const float C2 = 0.18033688011112042f;   // 0.125 * log2(e)

    const u16* qp = Q + ((size_t)bh * 4096 + qrow0 + colq) * 64 + quad * 8;
    bf16x8 aq0 = *(const bf16x8*)qp;
    bf16x8 aq1 = *(const bf16x8*)(qp + 32);

    float m_i[4], l_i[4];
    f32x4 o[4] = {};
#pragma unroll
    for (int i = 0; i < 4; ++i) { m_i[i] = -3.0e38f; l_i[i] = 0.f; }

#pragma unroll
    for (int c = 0; c < 2; ++c) {
        const int lo = EDGE ? ((c == 0) ? nt_lo : 12) : 0;
        const int hi = EDGE ? ((c == 0) ? ((nt_hi < 12) ? nt_hi : 12) : nt_hi) : 0;

        f32x4 sc[12];
        if constexpr (EDGE) {
#pragma unroll
            for (int j = 0; j < 12; ++j) sc[j] = (f32x4){0.f, 0.f, 0.f, 0.f};
#pragma unroll
            for (int j = 0; j < 12; ++j) {
                const int nt = c * 12 + j;
                if (nt >= lo && nt < hi) {
                    const u16* kp = Kb + ((size_t)bh * 4096 + key0 + nt * 16 + colq) * 64 + quad * 8;
                    bf16x8 b0 = *(const bf16x8*)kp;
                    bf16x8 b1 = *(const bf16x8*)(kp + 32);
                    f32x4 z = {0.f, 0.f, 0.f, 0.f};
                    __builtin_amdgcn_s_setprio(1);
                    z = __builtin_amdgcn_mfma_f32_16x16x32_bf16(aq0, b0, z, 0, 0, 0);
                    z = __builtin_amdgcn_mfma_f32_16x16x32_bf16(aq1, b1, z, 0, 0, 0);
                    __builtin_amdgcn_s_setprio(0);
                    sc[j] = z;
                }
            }
        } else {
            // interior: unconditional — compiler batches all 24 loads.
#pragma unroll
            for (int j = 0; j < 12; ++j) {
                const int nt = c * 12 + j;
                const u16* kp = Kb + ((size_t)bh * 4096 + key0 + nt * 16 + colq) * 64 + quad * 8;
                bf16x8 b0 = *(const bf16x8*)kp;
                bf16x8 b1 = *(const bf16x8*)(kp + 32);
                f32x4 z = {0.f, 0.f, 0.f, 0.f};
                __builtin_amdgcn_s_setprio(1);
                z = __builtin_amdgcn_mfma_f32_16x16x32_bf16(aq0, b0, z, 0, 0, 0);
                z = __builtin_amdgcn_mfma_f32_16x16x32_bf16(aq1, b1, z, 0, 0, 0);
                __builtin_amdgcn_s_setprio(0);
                sc[j] = z;
            }
        }
        // chunk row-max
        float mc[4];
#pragma unroll
        for (int i = 0; i < 4; ++i) mc[i] = -3.0e38f;
#pragma unroll
        for (int j = 0; j < 12; ++j) {
            if (EDGE) {
                const int nt = c * 12 + j;
                if (nt < lo || nt >= hi) continue;
            }
#pragma unroll
            for (int i = 0; i < 4; ++i) mc[i] = fmaxf(mc[i], sc[j][i]);
        }
#pragma unroll
        for (int i = 0; i < 4; ++i)
#pragma unroll
            for (int m = 8; m >= 1; m >>= 1) mc[i] = fmaxf(mc[i], __shfl_xor(mc[i], m, 64));
        // online-softmax update
        float a_i[4], psum[4];
#pragma unroll
        for (int i = 0; i < 4; ++i) {
            const float mn = fmaxf(m_i[i], mc[i]);
            a_i[i] = exp2f((m_i[i] - mn) * C2);
            m_i[i] = mn;
            psum[i] = 0.f;
        }
#pragma unroll
        for (int j = 0; j < 12; ++j) {
            if (EDGE) {
                const int nt = c * 12 + j;
                if (nt < lo || nt >= hi) continue;
            }
#pragma unroll
            for (int i = 0; i < 4; ++i) {
                const float p = exp2f((sc[j][i] - m_i[i]) * C2);
                psum[i] += p;
                Psw[(quad * 4 + i) * 200 + j * 16 + colq] = f2bf(p);
            }
        }
#pragma unroll
        for (int i = 0; i < 4; ++i)
#pragma unroll
            for (int m = 8; m >= 1; m >>= 1) psum[i] += __shfl_xor(psum[i], m, 64);
#pragma unroll
        for (int i = 0; i < 4; ++i) l_i[i] = l_i[i] * a_i[i] + psum[i];
#pragma unroll
        for (int dt = 0; dt < 4; ++dt)
#pragma unroll
            for (int i = 0; i < 4; ++i) o[dt][i] *= a_i[i];
        // PV over this chunk
        const int klo = EDGE ? ((lo - c * 12) >> 1) : 0;
        const int khi = EDGE ? ((hi - c * 12) >> 1) : 6;
#pragma unroll
        for (int k6 = 0; k6 < 6; ++k6) {
            if (EDGE && (k6 < klo || k6 >= khi)) continue;
            bf16x8 ap = *(const bf16x8*)(Psw + colq * 200 + k6 * 32 + quad * 8);
            const int kkk = key0 + (c * 6 + k6) * 32 + quad * 8;
            __builtin_amdgcn_s_setprio(1);
#pragma unroll
            for (int dt = 0; dt < 4; ++dt) {
                const u16* vp = Vt + ((size_t)bh * 64 + dt * 16 + colq) * 4096 + kkk;
                bf16x8 bv = *(const bf16x8*)vp;
                o[dt] = __builtin_amdgcn_mfma_f32_16x16x32_bf16(ap, bv, o[dt], 0, 0, 0);
            }
            __builtin_amdgcn_s_setprio(0);
        }
    }

    const int bb = bh >> 4, hh = bh & 15;
#pragma unroll
    for (int i = 0; i < 4; ++i) {
        const float inv = 1.0f / fmaxf(l_i[i], 1e-20f);
        const int t = qrow0 + quad * 4 + i;
        u16* op = out + ((size_t)(bb * 4096 + t)) * 1024 + hh * 64;
#pragma unroll
        for (int dt = 0; dt < 4; ++dt) op[dt * 16 + colq] = f2bf(o[dt][i] * inv);
    }
}

__global__ __launch_bounds__(256, 4) void attn_kernel(
    const u16* __restrict__ Q, const u16* __restrict__ Kb,
    const u16* __restrict__ Vt, u16* __restrict__ out)
{
    __shared__ u16 Ps[4][16 * 200];
    const int tid  = threadIdx.x;
    const int wave = tid >> 6;
    const int lane = tid & 63;
    const int colq = lane & 15;
    const int quad = lane >> 4;

    const int f   = blockIdx.x;            // 0..4095
    const int xcd = f & 7;
    const int s8  = f >> 3;                // 0..511
    const int bh  = s8 >> 3;               // 0..63
    const int tb  = (s8 & 7) + 8 * xcd;    // 0..63
    const int qrow0 = tb * 64 + wave * 16;
    const int nb    = tb >> 1;
    const int key0  = nb * 128 - 128;
    const int nt_lo = (nb == 0) ? 8 : 0;
    const int nt_hi = (nb == 31) ? 16 : 24;

    u16* Psw = &Ps[wave][0];

    if (nb != 0 && nb != 31) {
        attn_body<false>(Q, Kb, Vt, out, bh, qrow0, key0, nt_lo, nt_hi, Psw, colq, quad);
    } else {
        attn_body<true>(Q, Kb, Vt, out, bh, qrow0, key0, nt_lo, nt_hi, Psw, colq, quad);
    }
}

// ---------------------------------------------------------------------------
extern "C" void kernel_launch(void* const* d_in, const int* in_sizes, int n_in,
                              void* d_out, int out_size, void* d_ws, size_t ws_size,
                              hipStream_t stream)
{
    const float* x      = (const float*)d_in[0];
    const float* ln1_w  = (const float*)d_in[1];
    const float* ln1_b  = (const float*)d_in[2];
    const float* qkv_w  = (const float*)d_in[3];
    const float* qkv_b  = (const float*)d_in[4];
    const float* proj_w = (const float*)d_in[5];
    const float* proj_b = (const float*)d_in[6];
    const float* ln2_w  = (const float*)d_in[7];
    const float* ln2_b  = (const float*)d_in[8];
    const float* fc1_w  = (const float*)d_in[9];
    const float* fc1_b  = (const float*)d_in[10];
    const float* fc2_w  = (const float*)d_in[11];
    const float* fc2_b  = (const float*)d_in[12];
    float* outp = (float*)d_out;

    if (ws_size < 134217728u) return;
    char* ws = (char*)d_ws;
    u16* R0 = (u16*)(ws);               // bf16 weights (25.2 MB)
    u16* R1 = (u16*)(ws + 33554432);    // Q  -> x2 (bf16)
    u16* R2 = (u16*)(ws + 67108864);    // K  -> h lower half
    u16* R3 = (u16*)(ws + 100663296);   // Vt -> h upper half
    // d_out scratch: xn @ [0:33.5M), attn/yn @ [33.5M:67M).
    u16* xnc    = (u16*)d_out;
    u16* attn_o = (u16*)((char*)d_out + 33554432);

    u16* qkvwb  = R0;
    u16* projwb = R0 + 3145728;
    u16* fc1wb  = R0 + 4194304;
    u16* fc2wb  = R0 + 8388608;
    u16* Qb = R1, *Kb = R2, *Vtb = R3;
    u16* x2 = R1;                       // Q dead after attn
    u16* yn = attn_o;                   // attn_o dead after proj
    u16* hb = R2;                       // K,Vt dead after attn: 67 MB contiguous

    // 1. weights f32 -> bf16
    cvt_kernel<<<3072, 256, 0, stream>>>(qkv_w, qkvwb, 3145728);
    cvt_kernel<<<1024, 256, 0, stream>>>(proj_w, projwb, 1048576);
    cvt_kernel<<<4096, 256, 0, stream>>>(fc1_w, fc1wb, 4194304);
    cvt_kernel<<<4096, 256, 0, stream>>>(fc2_w, fc2wb, 4194304);
    // 2. LN1: x -> xn
    ln_kernel<true><<<4096, 256, 0, stream>>>(x, ln1_w, ln1_b, xnc);
    // 3. qkv GEMM + scatter (768 blocks)
    gemm256<0, 0, false, 4><<<dim3(12, 64), 512, 0, stream>>>(
        xnc, qkvwb, qkv_b, nullptr, nullptr, Qb, Kb, Vtb,
        16384, 3072, 1024, 1024, 1024, 0);
    // 4. local attention -> attn_o
    attn_kernel<<<4096, 256, 0, stream>>>(Qb, Kb, Vtb, attn_o);
    // 5. proj + residual(x, f32) -> x2 bf16 (256 blocks)
    gemm256<1, 1, false, 4><<<dim3(4, 64), 512, 0, stream>>>(
        attn_o, projwb, proj_b, x, nullptr, x2, nullptr, nullptr,
        16384, 1024, 1024, 1024, 1024, 0);
    // 6. LN2: x2 -> yn
    ln_kernel<false><<<4096, 256, 0, stream>>>(x2, ln2_w, ln2_b, yn);
    // 7. FFN in 2 M-chunks of 8192 rows; h (67 MB) in R2+R3.
    //    fc1: 512 blocks (BN=256). fc2: BN=128 variant -> 8x32 = 256 blocks.
    for (int ci = 0; ci < 2; ++ci) {
        const size_t off = (size_t)ci * 8192 * 1024;
        gemm256<2, 0, false, 4><<<dim3(16, 32), 512, 0, stream>>>(
            yn + off, fc1wb, fc1_b, nullptr, nullptr, hb, nullptr, nullptr,
            8192, 4096, 1024, 1024, 1024, 0);
        gemm256<1, 2, true, 2><<<dim3(8, 32), 512, 0, stream>>>(
            hb, fc2wb, fc2_b, nullptr, x2 + off, outp + off, nullptr, nullptr,
            8192, 1024, 4096, 4096, 4096, 0);
    }
}